// Round 1
// baseline (949.108 us; speedup 1.0000x reference)
//
#include <hip/hip_runtime.h>
#include <hip/hip_bf16.h>

// TripletMessage: N=50000 nodes, C=64 ch, H=3 heads, E=800000 edges (runtime).
// out[n,:] = (segment_sum_dst(softmax_dst(alpha) * e_ij * x_j) @ Wscale) + bias
// alpha[e,h] = lrelu( a0[dst,h] + a2[src,h] + <edge_attr[e], v1[h]> )

#define N_NODES 50000
#define CCH 64
#define HEADS 3
#define HC 192
#define NEG_SLOPE 0.2f

// ---------------- kernel 0: v1[h][k] = sum_c We[k, h*64+c] * Watt[h,1,c] ----
__global__ void k_prep(const float* __restrict__ We, const float* __restrict__ Watt,
                       float* __restrict__ v1) {
    int t = threadIdx.x;
    if (t >= HEADS * 16) return;
    int h = t / 16, k = t % 16;
    float s = 0.f;
    #pragma unroll
    for (int c = 0; c < CCH; ++c)
        s = fmaf(We[k * HC + h * CCH + c], Watt[h * HC + CCH + c], s);
    v1[t] = s;  // layout [h*16 + k]
}

// ---------------- kernel 1: x_proj = x @ Wn; a0/a2 per (node, head) ---------
// block 192 threads (3 waves; wave w == head w), 16 nodes per block
__global__ __launch_bounds__(192) void k_xproj(
    const float* __restrict__ x, const float* __restrict__ Wn,
    const float* __restrict__ Watt, float* __restrict__ x_proj,
    float* __restrict__ a0, float* __restrict__ a2) {
    __shared__ float wns[CCH * HC];   // 49152 B
    __shared__ float xs[16 * CCH];    // 4096 B
    int t = threadIdx.x;
    for (int i = t; i < CCH * HC; i += 192) wns[i] = Wn[i];
    int base = blockIdx.x * 16;
    for (int i = t; i < 16 * CCH; i += 192) {
        int idx = base * CCH + i;
        xs[i] = (idx < N_NODES * CCH) ? x[idx] : 0.f;
    }
    __syncthreads();
    int h = t >> 6, c = t & 63;
    float w0 = Watt[h * HC + c];            // w[h,0,c]
    float w2 = Watt[h * HC + 2 * CCH + c];  // w[h,2,c]
    #pragma unroll 1
    for (int j = 0; j < 16; ++j) {
        int n = base + j;
        if (n >= N_NODES) break;
        float val = 0.f;
        #pragma unroll
        for (int k = 0; k < CCH; ++k) val = fmaf(xs[j * CCH + k], wns[k * HC + t], val);
        x_proj[(size_t)n * HC + t] = val;
        float p0 = val * w0, p2 = val * w2;
        #pragma unroll
        for (int off = 32; off; off >>= 1) {
            p0 += __shfl_down(p0, off);
            p2 += __shfl_down(p2, off);
        }
        if (c == 0) { a0[n * HEADS + h] = p0; a2[n * HEADS + h] = p2; }
    }
}

// ---------------- kernel 2: alpha -> exp, denom atomicAdd -------------------
__global__ __launch_bounds__(256) void k_alpha(
    const int* __restrict__ ei, const float* __restrict__ ea,
    const float* __restrict__ a0, const float* __restrict__ a2,
    const float* __restrict__ v1, float* __restrict__ exp_a,
    float* __restrict__ denom, int E) {
    __shared__ float v1s[48];
    if (threadIdx.x < 48) v1s[threadIdx.x] = v1[threadIdx.x];
    __syncthreads();
    int e = blockIdx.x * 256 + threadIdx.x;
    if (e >= E) return;
    int src = ei[e];
    int dst = ei[E + e];
    const float4* ea4 = (const float4*)(ea + (size_t)e * 16);
    float at[16];
    #pragma unroll
    for (int q = 0; q < 4; ++q) {
        float4 v = ea4[q];
        at[q * 4 + 0] = v.x; at[q * 4 + 1] = v.y;
        at[q * 4 + 2] = v.z; at[q * 4 + 3] = v.w;
    }
    #pragma unroll
    for (int h = 0; h < HEADS; ++h) {
        float s = a0[dst * HEADS + h] + a2[src * HEADS + h];
        #pragma unroll
        for (int k = 0; k < 16; ++k) s = fmaf(at[k], v1s[h * 16 + k], s);
        s = (s >= 0.f) ? s : NEG_SLOPE * s;
        float ex = expf(s);
        exp_a[(size_t)h * E + e] = ex;           // SoA: coalesced
        atomicAdd(&denom[dst * HEADS + h], ex);
    }
}

// ---------------- kernel 3: message + scatter-add aggregation ---------------
// one wave (64 lanes) per edge; lane = channel c
__global__ __launch_bounds__(256) void k_msg(
    const int* __restrict__ ei, const float* __restrict__ ea,
    const float* __restrict__ x_proj, const float* __restrict__ We,
    const float* __restrict__ exp_a, const float* __restrict__ denom,
    float* __restrict__ aggr, int E) {
    int gid = blockIdx.x * 256 + threadIdx.x;
    int e = gid >> 6;
    int c = gid & 63;
    if (e >= E) return;
    int src = ei[e];
    int dst = ei[E + e];
    const float4* ea4 = (const float4*)(ea + (size_t)e * 16);
    float at[16];
    #pragma unroll
    for (int q = 0; q < 4; ++q) {
        float4 v = ea4[q];  // all lanes same address -> broadcast
        at[q * 4 + 0] = v.x; at[q * 4 + 1] = v.y;
        at[q * 4 + 2] = v.z; at[q * 4 + 3] = v.w;
    }
    #pragma unroll
    for (int h = 0; h < HEADS; ++h) {
        float ex = exp_a[(size_t)h * E + e];
        float d = denom[dst * HEADS + h] + 1e-16f;
        float coef = ex / d;
        float ev = 0.f;
        #pragma unroll
        for (int k = 0; k < 16; ++k)
            ev = fmaf(at[k], We[k * HC + h * CCH + c], ev);
        float xj = x_proj[(size_t)src * HC + h * CCH + c];
        atomicAdd(&aggr[(size_t)dst * HC + h * CCH + c], coef * ev * xj);
    }
}

// ---------------- kernel 4: out = aggr @ Ws + bias --------------------------
// block 256 = 4 groups of 64 lanes; 16 nodes per block; Ws staged in LDS
__global__ __launch_bounds__(256) void k_out(
    const float* __restrict__ aggr, const float* __restrict__ Ws,
    const float* __restrict__ bias, float* __restrict__ out) {
    __shared__ float wss[HC * CCH];   // 49152 B
    __shared__ float rows[4][HC];     // 3072 B
    int t = threadIdx.x;
    for (int i = t; i < HC * CCH; i += 256) wss[i] = Ws[i];
    int grp = t >> 6, c = t & 63;
    int base = blockIdx.x * 16;
    float b = bias[c];
    #pragma unroll 1
    for (int it = 0; it < 4; ++it) {
        int n = base + it * 4 + grp;
        __syncthreads();
        if (n < N_NODES) {
            for (int i = c; i < HC; i += 64) rows[grp][i] = aggr[(size_t)n * HC + i];
        }
        __syncthreads();
        if (n < N_NODES) {
            float s = b;
            #pragma unroll
            for (int k = 0; k < HC; ++k) s = fmaf(rows[grp][k], wss[k * CCH + c], s);
            out[(size_t)n * CCH + c] = s;
        }
    }
}

extern "C" void kernel_launch(void* const* d_in, const int* in_sizes, int n_in,
                              void* d_out, int out_size, void* d_ws, size_t ws_size,
                              hipStream_t stream) {
    const float* x    = (const float*)d_in[0];
    const int*   ei   = (const int*)d_in[1];
    const float* ea   = (const float*)d_in[2];
    const float* Wn   = (const float*)d_in[3];
    const float* We   = (const float*)d_in[4];
    const float* Watt = (const float*)d_in[5];
    const float* Ws   = (const float*)d_in[6];
    const float* bias = (const float*)d_in[7];
    float* out = (float*)d_out;

    const int E = in_sizes[1] / 2;

    // workspace layout (float offsets); denom+aggr contiguous for one memset
    float* w = (float*)d_ws;
    const size_t denom_off = 0;                          // 150000
    const size_t aggr_off  = 150016;                     // 9.6M
    const size_t xproj_off = aggr_off + (size_t)N_NODES * HC;   // 9,750,016
    const size_t a0_off    = xproj_off + (size_t)N_NODES * HC;  // +9.6M
    const size_t a2_off    = a0_off + N_NODES * HEADS;
    const size_t v1_off    = a2_off + N_NODES * HEADS;
    const size_t exp_off   = v1_off + 64;
    // total ~ (exp_off + 3E) * 4 bytes  ~= 88.2 MB

    float* denom  = w + denom_off;
    float* aggr   = w + aggr_off;
    float* x_proj = w + xproj_off;
    float* a0     = w + a0_off;
    float* a2     = w + a2_off;
    float* v1     = w + v1_off;
    float* exp_a  = w + exp_off;

    // zero denom..aggr in one shot (re-poisoned to 0xAA before every call)
    hipMemsetAsync(d_ws, 0, (aggr_off + (size_t)N_NODES * HC) * sizeof(float), stream);

    k_prep<<<1, 64, 0, stream>>>(We, Watt, v1);
    k_xproj<<<(N_NODES + 15) / 16, 192, 0, stream>>>(x, Wn, Watt, x_proj, a0, a2);
    k_alpha<<<(E + 255) / 256, 256, 0, stream>>>(ei, ea, a0, a2, v1, exp_a, denom, E);
    k_msg<<<((size_t)E * 64 + 255) / 256, 256, 0, stream>>>(ei, ea, x_proj, We, exp_a,
                                                            denom, aggr, E);
    k_out<<<(N_NODES + 15) / 16, 256, 0, stream>>>(aggr, Ws, bias, out);
}

// Round 2
// 532.398 us; speedup vs baseline: 1.7827x; 1.7827x over previous
//
#include <hip/hip_runtime.h>
#include <hip/hip_bf16.h>

// TripletMessage, CSR-grouped, atomic-free hot path.
// alpha[e,h] = lrelu( a0[dst,h] + a2[src,h] + <ea[e], v1[h]> )
// out[n]    = (sum_e softmax(alpha)*e_ij*x_j) @ Ws + bias, fused epilogue.

#define N_NODES 50000
#define CCH 64
#define HEADS 3
#define HC 192
#define NEG_SLOPE 0.2f

// ---------- k_prep: v1[h][k] = sum_c We[k, h*64+c] * Watt[h,1,c] ------------
__global__ void k_prep(const float* __restrict__ We, const float* __restrict__ Watt,
                       float* __restrict__ v1) {
    int t = threadIdx.x;
    if (t >= HEADS * 16) return;
    int h = t / 16, k = t % 16;
    float s = 0.f;
    #pragma unroll
    for (int c = 0; c < CCH; ++c)
        s = fmaf(We[k * HC + h * CCH + c], Watt[h * HC + CCH + c], s);
    v1[t] = s;  // [h*16+k]
}

// ---------- k_xproj: x_proj(bf16) + a0/a2 -----------------------------------
// 192 threads (wave==head), 16 nodes/block, Wn column cached in 64 VGPRs
__global__ __launch_bounds__(192) void k_xproj(
    const float* __restrict__ x, const float* __restrict__ Wn,
    const float* __restrict__ Watt, __hip_bfloat16* __restrict__ xph,
    float* __restrict__ a0, float* __restrict__ a2) {
    __shared__ float xs[16 * CCH];
    int t = threadIdx.x;
    float wreg[CCH];
    #pragma unroll
    for (int k = 0; k < CCH; ++k) wreg[k] = Wn[k * HC + t];  // coalesced per k
    int base = blockIdx.x * 16;
    for (int i = t; i < 16 * CCH; i += 192) {
        int idx = base * CCH + i;
        xs[i] = (idx < N_NODES * CCH) ? x[idx] : 0.f;
    }
    __syncthreads();
    int h = t >> 6, c = t & 63;
    float w0 = Watt[h * HC + c];
    float w2 = Watt[h * HC + 2 * CCH + c];
    #pragma unroll 1
    for (int j = 0; j < 16; ++j) {
        int n = base + j;
        if (n >= N_NODES) break;
        float val = 0.f;
        #pragma unroll
        for (int k = 0; k < CCH; k += 4) {
            float4 xv = *(const float4*)&xs[j * CCH + k];
            val = fmaf(xv.x, wreg[k], val);
            val = fmaf(xv.y, wreg[k + 1], val);
            val = fmaf(xv.z, wreg[k + 2], val);
            val = fmaf(xv.w, wreg[k + 3], val);
        }
        xph[(size_t)n * HC + t] = __float2bfloat16(val);
        float p0 = val * w0, p2 = val * w2;
        #pragma unroll
        for (int off = 32; off; off >>= 1) {
            p0 += __shfl_down(p0, off);
            p2 += __shfl_down(p2, off);
        }
        if (c == 0) { a0[n * HEADS + h] = p0; a2[n * HEADS + h] = p2; }
    }
}

// ---------- k_hist ----------------------------------------------------------
__global__ __launch_bounds__(256) void k_hist(const int* __restrict__ ei,
                                              int* __restrict__ cnt, int E) {
    int e = blockIdx.x * 256 + threadIdx.x;
    if (e < E) atomicAdd(&cnt[ei[E + e]], 1);
}

// ---------- k_scan: exclusive prefix sum over cnt[0..N) (single block) ------
__global__ __launch_bounds__(1024) void k_scan(const int* __restrict__ cnt,
                                               int* __restrict__ off,
                                               int* __restrict__ cursor) {
    __shared__ int wsum[16];
    __shared__ int carry_s;
    int t = threadIdx.x, lane = t & 63, wid = t >> 6;
    if (t == 0) carry_s = 0;
    __syncthreads();
    for (int base = 0; base < N_NODES; base += 1024) {
        int i = base + t;
        int v = (i < N_NODES) ? cnt[i] : 0;
        int x = v;
        #pragma unroll
        for (int o = 1; o < 64; o <<= 1) {
            int y = __shfl_up(x, o);
            if (lane >= o) x += y;
        }
        if (lane == 63) wsum[wid] = x;
        __syncthreads();
        if (wid == 0) {
            int s = (lane < 16) ? wsum[lane] : 0;
            #pragma unroll
            for (int o = 1; o < 16; o <<= 1) {
                int y = __shfl_up(s, o);
                if (lane >= o) s += y;
            }
            if (lane < 16) wsum[lane] = s;  // inclusive wave sums
        }
        __syncthreads();
        int woff = (wid > 0) ? wsum[wid - 1] : 0;
        int incl = carry_s + woff + x;
        int excl = incl - v;
        if (i < N_NODES) { off[i] = excl; cursor[i] = excl; }
        __syncthreads();
        if (t == 1023) carry_s = incl;
        __syncthreads();
    }
    if (t == 0) off[N_NODES] = carry_s;
}

// ---------- k_place: scatter edges into CSR order ---------------------------
// writes csr_src, ea_csr (reordered edge_attr), b = <ea,v1[h]> + a2[src,h]
__global__ __launch_bounds__(256) void k_place(
    const int* __restrict__ ei, const float* __restrict__ ea,
    const float* __restrict__ a2, const float* __restrict__ v1,
    int* __restrict__ cursor, int* __restrict__ csr_src,
    float* __restrict__ bv, float* __restrict__ ea_csr, int E) {
    __shared__ float v1s[48];
    if (threadIdx.x < 48) v1s[threadIdx.x] = v1[threadIdx.x];
    __syncthreads();
    int e = blockIdx.x * 256 + threadIdx.x;
    if (e >= E) return;
    int src = ei[e], dst = ei[E + e];
    const float4* q = (const float4*)(ea + (size_t)e * 16);
    float4 q0 = q[0], q1 = q[1], q2 = q[2], q3 = q[3];
    float at[16] = {q0.x, q0.y, q0.z, q0.w, q1.x, q1.y, q1.z, q1.w,
                    q2.x, q2.y, q2.z, q2.w, q3.x, q3.y, q3.z, q3.w};
    int pos = atomicAdd(&cursor[dst], 1);
    #pragma unroll
    for (int h = 0; h < HEADS; ++h) {
        float s = a2[src * HEADS + h];
        #pragma unroll
        for (int j = 0; j < 16; ++j) s = fmaf(at[j], v1s[h * 16 + j], s);
        bv[(size_t)pos * HEADS + h] = s;
    }
    csr_src[pos] = src;
    float4* o = (float4*)(ea_csr + (size_t)pos * 16);
    o[0] = q0; o[1] = q1; o[2] = q2; o[3] = q3;
}

// ---------- k_msg: wave-per-node message pass + fused Ws epilogue -----------
// 512 threads = 8 waves = 8 nodes/block; Ws staged once per block in LDS
__global__ __launch_bounds__(512, 4) void k_msg(
    const int* __restrict__ off, const int* __restrict__ csr_src,
    const float* __restrict__ bv, const float* __restrict__ ea_csr,
    const float* __restrict__ a0, const __hip_bfloat16* __restrict__ xph,
    const float* __restrict__ We, const float* __restrict__ Ws,
    const float* __restrict__ bias, float* __restrict__ out) {
    __shared__ float wss[HC * CCH];    // 48 KiB
    __shared__ float rows[8][HC];      // 6 KiB
    int t = threadIdx.x, lane = t & 63, wid = t >> 6, c = lane;
    // stage Ws
    {
        float4* d4 = (float4*)wss;
        const float4* s4 = (const float4*)Ws;
        for (int i = t; i < HC * CCH / 4; i += 512) d4[i] = s4[i];
    }
    // per-lane We columns for e_ij recompute: We[j, h*64+c]
    float weR[HEADS][16];
    #pragma unroll
    for (int h = 0; h < HEADS; ++h)
        #pragma unroll
        for (int j = 0; j < 16; ++j)
            weR[h][j] = We[j * HC + h * CCH + c];

    int n = blockIdx.x * 8 + wid;
    bool valid = n < N_NODES;
    int rs = 0, re = 0;
    float a00 = 0.f, a01 = 0.f, a02 = 0.f;
    if (valid) {
        rs = off[n]; re = off[n + 1];
        a00 = a0[n * HEADS + 0];
        a01 = a0[n * HEADS + 1];
        a02 = a0[n * HEADS + 2];
    }
    rs = __builtin_amdgcn_readfirstlane(rs);
    re = __builtin_amdgcn_readfirstlane(re);
    float acc0 = 0.f, acc1 = 0.f, acc2 = 0.f;
    float den0 = 0.f, den1 = 0.f, den2 = 0.f;
    for (int k = rs; k < re; ++k) {
        int src = __builtin_amdgcn_readfirstlane(csr_src[k]);
        const float* bp = bv + (size_t)k * HEADS;
        float al0 = a00 + bp[0];
        float al1 = a01 + bp[1];
        float al2 = a02 + bp[2];
        al0 = (al0 >= 0.f) ? al0 : NEG_SLOPE * al0;
        al1 = (al1 >= 0.f) ? al1 : NEG_SLOPE * al1;
        al2 = (al2 >= 0.f) ? al2 : NEG_SLOPE * al2;
        float ex0 = __expf(al0), ex1 = __expf(al1), ex2 = __expf(al2);
        den0 += ex0; den1 += ex1; den2 += ex2;
        const float4* eq = (const float4*)(ea_csr + (size_t)k * 16);
        float4 q0 = eq[0], q1 = eq[1], q2 = eq[2], q3 = eq[3];
        float at[16] = {q0.x, q0.y, q0.z, q0.w, q1.x, q1.y, q1.z, q1.w,
                        q2.x, q2.y, q2.z, q2.w, q3.x, q3.y, q3.z, q3.w};
        float ev0 = 0.f, ev1 = 0.f, ev2 = 0.f;
        #pragma unroll
        for (int j = 0; j < 16; ++j) {
            ev0 = fmaf(at[j], weR[0][j], ev0);
            ev1 = fmaf(at[j], weR[1][j], ev1);
            ev2 = fmaf(at[j], weR[2][j], ev2);
        }
        const __hip_bfloat16* xp = xph + (size_t)src * HC + c;
        float xj0 = __bfloat162float(xp[0]);
        float xj1 = __bfloat162float(xp[CCH]);
        float xj2 = __bfloat162float(xp[2 * CCH]);
        acc0 = fmaf(ex0 * ev0, xj0, acc0);
        acc1 = fmaf(ex1 * ev1, xj1, acc1);
        acc2 = fmaf(ex2 * ev2, xj2, acc2);
    }
    if (valid) {
        rows[wid][c]           = acc0 / (den0 + 1e-16f);
        rows[wid][CCH + c]     = acc1 / (den1 + 1e-16f);
        rows[wid][2 * CCH + c] = acc2 / (den2 + 1e-16f);
    }
    __syncthreads();
    if (valid) {
        float val = bias[c];
        #pragma unroll
        for (int k = 0; k < HC; k += 4) {
            float4 r = *(const float4*)&rows[wid][k];
            val = fmaf(r.x, wss[k * CCH + c], val);
            val = fmaf(r.y, wss[(k + 1) * CCH + c], val);
            val = fmaf(r.z, wss[(k + 2) * CCH + c], val);
            val = fmaf(r.w, wss[(k + 3) * CCH + c], val);
        }
        out[(size_t)n * CCH + c] = val;
    }
}

extern "C" void kernel_launch(void* const* d_in, const int* in_sizes, int n_in,
                              void* d_out, int out_size, void* d_ws, size_t ws_size,
                              hipStream_t stream) {
    const float* x    = (const float*)d_in[0];
    const int*   ei   = (const int*)d_in[1];
    const float* ea   = (const float*)d_in[2];
    const float* Wn   = (const float*)d_in[3];
    const float* We   = (const float*)d_in[4];
    const float* Watt = (const float*)d_in[5];
    const float* Ws   = (const float*)d_in[6];
    const float* bias = (const float*)d_in[7];
    float* out = (float*)d_out;

    const int E = in_sizes[1] / 2;

    // workspace layout (4-byte slots); total ~84.8 MB
    char* w = (char*)d_ws;
    size_t o = 0;
    int*   cnt     = (int*)(w + o);   o += 50048 * 4;          // zeroed
    int*   off     = (int*)(w + o);   o += 50064 * 4;
    int*   cursor  = (int*)(w + o);   o += 50048 * 4;
    float* v1      = (float*)(w + o); o += 64 * 4;
    float* a0      = (float*)(w + o); o += 150016 * 4;
    float* a2      = (float*)(w + o); o += 150016 * 4;
    int*   csr_src = (int*)(w + o);   o += (size_t)E * 4;
    float* bv      = (float*)(w + o); o += (size_t)E * HEADS * 4;
    __hip_bfloat16* xph = (__hip_bfloat16*)(w + o); o += (size_t)N_NODES * HC * 2;
    float* ea_csr  = (float*)(w + o); o += (size_t)E * 16 * 4;

    hipMemsetAsync(cnt, 0, 50048 * 4, stream);

    k_prep<<<1, 64, 0, stream>>>(We, Watt, v1);
    k_xproj<<<(N_NODES + 15) / 16, 192, 0, stream>>>(x, Wn, Watt, xph, a0, a2);
    k_hist<<<(E + 255) / 256, 256, 0, stream>>>(ei, cnt, E);
    k_scan<<<1, 1024, 0, stream>>>(cnt, off, cursor);
    k_place<<<(E + 255) / 256, 256, 0, stream>>>(ei, ea, a2, v1, cursor,
                                                 csr_src, bv, ea_csr, E);
    k_msg<<<(N_NODES + 7) / 8, 512, 0, stream>>>(off, csr_src, bv, ea_csr, a0,
                                                 xph, We, Ws, bias, out);
}